// Round 3
// baseline (353.169 us; speedup 1.0000x reference)
//
#include <hip/hip_runtime.h>
#include <stdint.h>

#define SEQ 2048
#define C3 3072
#define C1 1024

typedef __bf16 bf16x8 __attribute__((ext_vector_type(8)));
typedef short short8 __attribute__((ext_vector_type(8)));
typedef float f32x4 __attribute__((ext_vector_type(4)));
typedef float f32x16 __attribute__((ext_vector_type(16)));
typedef const __attribute__((address_space(1))) void gv_t;
typedef __attribute__((address_space(3))) void lv_t;

#if __has_builtin(__builtin_amdgcn_exp2f)
#define EXP2(x) __builtin_amdgcn_exp2f(x)
#else
#define EXP2(x) exp2f(x)
#endif

static __device__ __forceinline__ unsigned short f2bf(float f) {
  union { float ff; unsigned u; } x; x.ff = f;
  unsigned u = x.u + 0x7FFFu + ((x.u >> 16) & 1u);
  return (unsigned short)(u >> 16);
}
static __device__ __forceinline__ unsigned rne2(float lo, float hi) {
  return (unsigned)f2bf(lo) | ((unsigned)f2bf(hi) << 16);
}
// pack top halves of two f32 -> one bf16x2 dword (truncation; P in [0,1])
static __device__ __forceinline__ unsigned pk2(float lo, float hi) {
  union { float f; unsigned u; } a, b; a.f = lo; b.f = hi;
  return __builtin_amdgcn_perm(b.u, a.u, 0x07060302);
}

__global__ void k_cvt(const float* __restrict__ in, unsigned short* __restrict__ out, int n4) {
  int i = blockIdx.x * 256 + threadIdx.x;
  if (i >= n4) return;
  f32x4 v = ((const f32x4*)in)[i];
  ushort4 o;
  o.x = f2bf(v[0]); o.y = f2bf(v[1]); o.z = f2bf(v[2]); o.w = f2bf(v[3]);
  ((ushort4*)out)[i] = o;
}

// C[M,N] = A[M,K] @ B[N,K]^T, bf16 in, BK=64 (half the barrier drains vs BK=32;
// 32 KB LDS keeps 3 blocks/CU unlike m132's 64 KB regression).
// MODE 0: bf16 out, cols<1024 scaled by 0.125*log2(e). MODE 1: f32 out + bias.
template<int MODE>
__global__ __launch_bounds__(256, 2) void k_gemm(
    const unsigned short* __restrict__ A, const unsigned short* __restrict__ B,
    void* __restrict__ Cout, const float* __restrict__ bias, int M, int N, int K)
{
  __shared__ unsigned short As[128 * 64];
  __shared__ unsigned short Bs[128 * 64];
  const int tid = threadIdx.x;
  const int w = tid >> 6, l = tid & 63;
  const int lane15 = l & 15, quad = l >> 4;
  const int m0 = blockIdx.y * 128, n0 = blockIdx.x * 128;
  const int wm = (w >> 1) * 64, wn = (w & 1) * 64;

  f32x4 acc[4][4];
#pragma unroll
  for (int i = 0; i < 4; i++)
#pragma unroll
    for (int j = 0; j < 4; j++) acc[i][j] = (f32x4){0.f, 0.f, 0.f, 0.f};

  // staging: lane -> row (l>>3), slot (l&7); slot c of row r holds global chunk c^(r&7)
  const int srow = l >> 3;
  const int g_off = ((l & 7) ^ (srow & 7)) * 8;
  const unsigned short* Ab = A + (size_t)(m0 + w * 32 + srow) * K + g_off;
  const unsigned short* Bb = B + (size_t)(n0 + w * 32 + srow) * K + g_off;
  const int rsl = lane15 & 7;  // frag-read swizzle key

  for (int k0 = 0; k0 < K; k0 += 64) {
    __syncthreads();
#pragma unroll
    for (int i = 0; i < 4; i++) {
      int rb = w * 32 + i * 8;
      __builtin_amdgcn_global_load_lds((gv_t*)(Ab + (size_t)(i * 8) * K + k0),
                                       (lv_t*)&As[rb * 64], 16, 0, 0);
      __builtin_amdgcn_global_load_lds((gv_t*)(Bb + (size_t)(i * 8) * K + k0),
                                       (lv_t*)&Bs[rb * 64], 16, 0, 0);
    }
    __syncthreads();
#pragma unroll
    for (int s = 0; s < 2; s++) {
      bf16x8 af[4], bfr[4];
      const int slot = ((s * 4 + quad) ^ rsl) * 8;
#pragma unroll
      for (int t = 0; t < 4; t++) {
        af[t]  = *(const bf16x8*)&As[(wm + t * 16 + lane15) * 64 + slot];
        bfr[t] = *(const bf16x8*)&Bs[(wn + t * 16 + lane15) * 64 + slot];
      }
#pragma unroll
      for (int i = 0; i < 4; i++)
#pragma unroll
        for (int j = 0; j < 4; j++)
          acc[i][j] = __builtin_amdgcn_mfma_f32_16x16x32_bf16(af[i], bfr[j], acc[i][j], 0, 0, 0);
    }
  }

  if (MODE == 0) {
    unsigned short* Cp = (unsigned short*)Cout;
#pragma unroll
    for (int i = 0; i < 4; i++) {
      int rowb = m0 + wm + i * 16 + quad * 4;
#pragma unroll
      for (int j = 0; j < 4; j++) {
        int col = n0 + wn + j * 16 + lane15;
        float s = (col < 1024) ? 0.18033688f : 1.0f;  // 0.125 * log2(e)
#pragma unroll
        for (int r = 0; r < 4; r++)
          Cp[(size_t)(rowb + r) * N + col] = f2bf(acc[i][j][r] * s);
      }
    }
  } else {
    float* Cp = (float*)Cout;
#pragma unroll
    for (int i = 0; i < 4; i++) {
      int rowb = m0 + wm + i * 16 + quad * 4;
#pragma unroll
      for (int j = 0; j < 4; j++) {
        int col = n0 + wn + j * 16 + lane15;
        float bv = bias[col];
#pragma unroll
        for (int r = 0; r < 4; r++)
          Cp[(size_t)(rowb + r) * N + col] = acc[i][j][r] + bv;
      }
    }
  }
}

// V transpose: qkv V-block [tok][h*64+d] -> vT[(bh*64+d)][tok]
__global__ void k_vt(const unsigned short* __restrict__ qkv, unsigned short* __restrict__ vT) {
  __shared__ unsigned short T[64 * 65];
  int t = threadIdx.x;
  int bh = blockIdx.y, b = bh >> 4, h = bh & 15;
  int t0 = blockIdx.x * 64;
  int tokl = t >> 2, dl = (t & 3) * 16;
  const unsigned short* g = qkv + (size_t)(b * SEQ + t0 + tokl) * C3 + 2 * C1 + h * 64 + dl;
  short8 v0 = *(const short8*)g;
  short8 v1 = *(const short8*)(g + 8);
#pragma unroll
  for (int j = 0; j < 8; j++) {
    T[(dl + j) * 65 + tokl]     = (unsigned short)v0[j];
    T[(dl + 8 + j) * 65 + tokl] = (unsigned short)v1[j];
  }
  __syncthreads();
  int d2 = t >> 2, tk = (t & 3) * 16;
  union { unsigned short s[16]; short8 v[2]; } o;
#pragma unroll
  for (int j = 0; j < 16; j++) o.s[j] = T[d2 * 65 + tk + j];
  unsigned short* og = vT + ((size_t)bh * 64 + d2) * SEQ + t0 + tk;
  *(short8*)og = o.v[0];
  *(short8*)(og + 8) = o.v[1];
}

// Flash attention, 32x32x16 MFMA, 4 waves x 32 q = 128 q per block.
// Single 32 KB LDS buffer (Ks 16K | Vt 16K) + 2-barrier staging -> 3 blocks/CU
// (m97 structure; round-2's 64 KB double-buffer capped occupancy at 2 and lost).
// S^T[key][q] (q = lane&31): softmax in-lane; wave-uniform causal skip of
// fully-masked 32-key sub-tiles on the diagonal.
__global__ __launch_bounds__(256, 3) void k_attn(
    const unsigned short* __restrict__ qkv, const unsigned short* __restrict__ vT,
    unsigned short* __restrict__ att)
{
  __shared__ unsigned short buf[16384];  // Ks 128x64 | Vt 64x128
  const int tid = threadIdx.x;
  const int w = tid >> 6, l = tid & 63;
  const int l31 = l & 31, hl = l >> 5;
  const int bh = blockIdx.x, b = bh >> 4, h = bh & 15;
  const int qt = (int)(gridDim.y - 1 - blockIdx.y);  // globally heavy-first
  const int q0 = qt * 128;
  const int nkt = qt + 1;
  const size_t tokb = (size_t)b * SEQ;
  const int qmy = q0 + w * 32 + l31;

  // Q B-frags (global, once): B[k=d][n=q], k = hl*8+j within kstep
  bf16x8 qf[4];
  {
    const unsigned short* qp = qkv + (tokb + q0 + w * 32 + l31) * C3 + h * 64 + hl * 8;
#pragma unroll
    for (int ks = 0; ks < 4; ks++) qf[ks] = *(const bf16x8*)(qp + ks * 16);
  }

  f32x16 O[2];
#pragma unroll
  for (int i = 0; i < 16; i++) { O[0][i] = 0.f; O[1][i] = 0.f; }
  float mrun = -1e30f, lrun = 0.f;

  const int krow_l = l >> 3, kslot = l & 7;
  const int vrow_l = l >> 4, vslot = l & 15;
  unsigned short* Kb = &buf[0];
  unsigned short* Vb = &buf[8192];

  for (int kt = 0; kt < nkt; kt++) {
    const int k0 = kt << 7;
    __syncthreads();  // prev-tile reads done
    {
#pragma unroll
      for (int i = 0; i < 4; i++) {
        int rb = (w * 4 + i) * 8;
        int row = rb + krow_l;
        int ck = kslot ^ (row & 7);
        const unsigned short* g = qkv + (tokb + k0 + row) * C3 + C1 + h * 64 + ck * 8;
        __builtin_amdgcn_global_load_lds((gv_t*)g, (lv_t*)&Kb[rb * 64], 16, 0, 0);
      }
#pragma unroll
      for (int i = 0; i < 4; i++) {
        int rb = (w * 4 + i) * 4;
        int row = rb + vrow_l;
        int ck = vslot ^ (row & 15);
        const unsigned short* g = vT + ((size_t)bh * 64 + row) * SEQ + k0 + ck * 8;
        __builtin_amdgcn_global_load_lds((gv_t*)g, (lv_t*)&Vb[rb * 128], 16, 0, 0);
      }
    }
    __syncthreads();  // staging landed (vmcnt drain; hidden by other blocks)

    const bool diag = (kt == nkt - 1);
    const int mtEnd = diag ? (w + 1) : 4;

    // S^T = K @ Q^T : C[key][q]
    f32x16 st[4];
#pragma unroll
    for (int mt = 0; mt < 4; mt++) {
      if (mt >= mtEnd) continue;  // wave-uniform causal skip
#pragma unroll
      for (int i = 0; i < 16; i++) st[mt][i] = 0.f;
      int row = mt * 32 + l31;
      const unsigned short* kr = &Kb[row * 64];
#pragma unroll
      for (int ks = 0; ks < 4; ks++) {
        bf16x8 a = *(const bf16x8*)&kr[((((ks << 1) | hl)) ^ (row & 7)) * 8];
        st[mt] = __builtin_amdgcn_mfma_f32_32x32x16_bf16(a, qf[ks], st[mt], 0, 0, 0);
      }
    }

    if (diag) {  // partial mask only in the mt == w sub-tile
#pragma unroll
      for (int r = 0; r < 16; r++) {
        int key = k0 + w * 32 + (r & 3) + ((r >> 2) << 3) + (hl << 2);
        if (key > qmy) st[w][r] = -1e30f;
      }
    }

    float vmax = -1e30f;
#pragma unroll
    for (int mt = 0; mt < 4; mt++) {
      if (mt >= mtEnd) continue;
#pragma unroll
      for (int r = 0; r < 16; r++) vmax = fmaxf(vmax, st[mt][r]);
    }
    vmax = fmaxf(vmax, __shfl_xor(vmax, 32, 64));
    float mnew = fmaxf(mrun, vmax);
    float alpha = EXP2(mrun - mnew);

    float psum = 0.f;
    unsigned pk[4][8];
#pragma unroll
    for (int mt = 0; mt < 4; mt++) {
      if (mt >= mtEnd) continue;
#pragma unroll
      for (int r = 0; r < 16; r++) {
        float pv = EXP2(st[mt][r] - mnew);
        st[mt][r] = pv;
        psum += pv;
      }
#pragma unroll
      for (int k2 = 0; k2 < 8; k2++)
        pk[mt][k2] = pk2(st[mt][2 * k2], st[mt][2 * k2 + 1]);
    }
    psum += __shfl_xor(psum, 32, 64);
    lrun = lrun * alpha + psum;
    mrun = mnew;

#pragma unroll
    for (int i = 0; i < 16; i++) { O[0][i] *= alpha; O[1][i] *= alpha; }

    // O^T += V^T @ P^T  (P^T C->B layout: one shfl_xor(32) pair + selects per kstep)
#pragma unroll
    for (int ks = 0; ks < 8; ks++) {
      if (ks >= 2 * mtEnd) continue;
      int mt = ks >> 1, e = ks & 1;
      unsigned pA0 = pk[mt][4 * e], pA1 = pk[mt][4 * e + 1];
      unsigned pB0 = pk[mt][4 * e + 2], pB1 = pk[mt][4 * e + 3];
      unsigned w0 = hl ? pA0 : pB0, w1 = hl ? pA1 : pB1;
      unsigned r0 = (unsigned)__shfl_xor((int)w0, 32, 64);
      unsigned r1 = (unsigned)__shfl_xor((int)w1, 32, 64);
      unsigned s0 = hl ? pB0 : pA0, s1 = hl ? pB1 : pA1;
      union { unsigned u[4]; bf16x8 v; } Bf;
      Bf.u[0] = hl ? r0 : s0; Bf.u[1] = hl ? r1 : s1;
      Bf.u[2] = hl ? s0 : r0; Bf.u[3] = hl ? s1 : r1;
#pragma unroll
      for (int dt = 0; dt < 2; dt++) {
        int row = dt * 32 + l31;
        bf16x8 a = *(const bf16x8*)&Vb[row * 128 + (((2 * ks + hl)) ^ (row & 15)) * 8];
        O[dt] = __builtin_amdgcn_mfma_f32_32x32x16_bf16(a, Bf.v, O[dt], 0, 0, 0);
      }
    }
  }

  // epilogue: O^T (C-layout) -> LDS [q][d] -> coalesced bf16 store
  __syncthreads();  // all waves done reading buf before overlay
  float linv = __builtin_amdgcn_rcpf(lrun);
  unsigned* epi32 = (unsigned*)&buf[0];
  const int base = w * 2304 + l31 * 72;
#pragma unroll
  for (int dt = 0; dt < 2; dt++)
#pragma unroll
    for (int c = 0; c < 4; c++) {
      int d0 = dt * 32 + c * 8 + hl * 4;
      epi32[(base + d0) >> 1]     = rne2(O[dt][4 * c] * linv, O[dt][4 * c + 1] * linv);
      epi32[(base + d0 + 2) >> 1] = rne2(O[dt][4 * c + 2] * linv, O[dt][4 * c + 3] * linv);
    }
  __builtin_amdgcn_s_waitcnt(0);  // lgkm drain before cross-lane read (same wave)
  {
    int q = l >> 1, hf = l & 1;
    const unsigned short* ep = &buf[w * 2304 + q * 72 + hf * 32];
    unsigned short* og = att + (tokb + q0 + w * 32 + q) * C1 + h * 64 + hf * 32;
#pragma unroll
    for (int c2 = 0; c2 < 4; c2++)
      *(bf16x8*)(og + c2 * 8) = *(const bf16x8*)&ep[c2 * 8];
  }
}

extern "C" void kernel_launch(void* const* d_in, const int* in_sizes, int n_in,
                              void* d_out, int out_size, void* d_ws, size_t ws_size,
                              hipStream_t stream) {
  const float* x     = (const float*)d_in[0];
  const float* w_qkv = (const float*)d_in[1];
  const float* w_out = (const float*)d_in[2];
  const float* b_out = (const float*)d_in[3];
  float* out = (float*)d_out;

  unsigned short* xb  = (unsigned short*)d_ws;
  unsigned short* wqb = xb  + (size_t)8192 * 1024;
  unsigned short* wob = wqb + (size_t)3072 * 1024;
  unsigned short* qkv = wob + (size_t)1024 * 1024;
  unsigned short* att = qkv + (size_t)8192 * 3072;
  unsigned short* vT  = att + (size_t)8192 * 1024;

  k_cvt<<<8192, 256, 0, stream>>>(x, xb, 8192 * 1024 / 4);
  k_cvt<<<3072, 256, 0, stream>>>(w_qkv, wqb, 3072 * 1024 / 4);
  k_cvt<<<1024, 256, 0, stream>>>(w_out, wob, 1024 * 1024 / 4);
  k_gemm<0><<<dim3(24, 64), 256, 0, stream>>>(xb, wqb, (void*)qkv, nullptr, 8192, 3072, 1024);
  k_vt<<<dim3(32, 64), 256, 0, stream>>>(qkv, vT);
  k_attn<<<dim3(64, 16), 256, 0, stream>>>(qkv, vT, att);
  k_gemm<1><<<dim3(8, 64), 256, 0, stream>>>(att, wob, (void*)out, b_out, 8192, 1024, 1024);
}

// Round 4
// 231.692 us; speedup vs baseline: 1.5243x; 1.5243x over previous
//
#include <hip/hip_runtime.h>
#include <stdint.h>

#define SEQ 2048
#define C3 3072
#define C1 1024

typedef __bf16 bf16x8 __attribute__((ext_vector_type(8)));
typedef short short8 __attribute__((ext_vector_type(8)));
typedef float f32x4 __attribute__((ext_vector_type(4)));
typedef float f32x16 __attribute__((ext_vector_type(16)));
typedef const __attribute__((address_space(1))) void gv_t;
typedef __attribute__((address_space(3))) void lv_t;

#if __has_builtin(__builtin_amdgcn_exp2f)
#define EXP2(x) __builtin_amdgcn_exp2f(x)
#else
#define EXP2(x) exp2f(x)
#endif

static __device__ __forceinline__ unsigned short f2bf(float f) {
  union { float ff; unsigned u; } x; x.ff = f;
  unsigned u = x.u + 0x7FFFu + ((x.u >> 16) & 1u);
  return (unsigned short)(u >> 16);
}
static __device__ __forceinline__ unsigned rne2(float lo, float hi) {
  return (unsigned)f2bf(lo) | ((unsigned)f2bf(hi) << 16);
}
// pack top halves of two f32 -> one bf16x2 dword (truncation; P in [0,1])
static __device__ __forceinline__ unsigned pk2(float lo, float hi) {
  union { float f; unsigned u; } a, b; a.f = lo; b.f = hi;
  return __builtin_amdgcn_perm(b.u, a.u, 0x07060302);
}

__global__ void k_cvt(const float* __restrict__ in, unsigned short* __restrict__ out, int n4) {
  int i = blockIdx.x * 256 + threadIdx.x;
  if (i >= n4) return;
  f32x4 v = ((const f32x4*)in)[i];
  ushort4 o;
  o.x = f2bf(v[0]); o.y = f2bf(v[1]); o.z = f2bf(v[2]); o.w = f2bf(v[3]);
  ((ushort4*)out)[i] = o;
}

// C[M,N] = A[M,K] @ B[N,K]^T, bf16 in, BK=64.
// MODE 0: bf16 out, cols<1024 scaled by 0.125*log2(e). MODE 1: f32 out + bias.
template<int MODE>
__global__ __launch_bounds__(256, 2) void k_gemm(
    const unsigned short* __restrict__ A, const unsigned short* __restrict__ B,
    void* __restrict__ Cout, const float* __restrict__ bias, int M, int N, int K)
{
  __shared__ unsigned short As[128 * 64];
  __shared__ unsigned short Bs[128 * 64];
  const int tid = threadIdx.x;
  const int w = tid >> 6, l = tid & 63;
  const int lane15 = l & 15, quad = l >> 4;
  const int m0 = blockIdx.y * 128, n0 = blockIdx.x * 128;
  const int wm = (w >> 1) * 64, wn = (w & 1) * 64;

  f32x4 acc[4][4];
#pragma unroll
  for (int i = 0; i < 4; i++)
#pragma unroll
    for (int j = 0; j < 4; j++) acc[i][j] = (f32x4){0.f, 0.f, 0.f, 0.f};

  const int srow = l >> 3;
  const int g_off = ((l & 7) ^ (srow & 7)) * 8;
  const unsigned short* Ab = A + (size_t)(m0 + w * 32 + srow) * K + g_off;
  const unsigned short* Bb = B + (size_t)(n0 + w * 32 + srow) * K + g_off;
  const int rsl = lane15 & 7;

  for (int k0 = 0; k0 < K; k0 += 64) {
    __syncthreads();
#pragma unroll
    for (int i = 0; i < 4; i++) {
      int rb = w * 32 + i * 8;
      __builtin_amdgcn_global_load_lds((gv_t*)(Ab + (size_t)(i * 8) * K + k0),
                                       (lv_t*)&As[rb * 64], 16, 0, 0);
      __builtin_amdgcn_global_load_lds((gv_t*)(Bb + (size_t)(i * 8) * K + k0),
                                       (lv_t*)&Bs[rb * 64], 16, 0, 0);
    }
    __syncthreads();
#pragma unroll
    for (int s = 0; s < 2; s++) {
      bf16x8 af[4], bfr[4];
      const int slot = ((s * 4 + quad) ^ rsl) * 8;
#pragma unroll
      for (int t = 0; t < 4; t++) {
        af[t]  = *(const bf16x8*)&As[(wm + t * 16 + lane15) * 64 + slot];
        bfr[t] = *(const bf16x8*)&Bs[(wn + t * 16 + lane15) * 64 + slot];
      }
#pragma unroll
      for (int i = 0; i < 4; i++)
#pragma unroll
        for (int j = 0; j < 4; j++)
          acc[i][j] = __builtin_amdgcn_mfma_f32_16x16x32_bf16(af[i], bfr[j], acc[i][j], 0, 0, 0);
    }
  }

  if (MODE == 0) {
    unsigned short* Cp = (unsigned short*)Cout;
#pragma unroll
    for (int i = 0; i < 4; i++) {
      int rowb = m0 + wm + i * 16 + quad * 4;
#pragma unroll
      for (int j = 0; j < 4; j++) {
        int col = n0 + wn + j * 16 + lane15;
        float s = (col < 1024) ? 0.18033688f : 1.0f;  // 0.125 * log2(e)
#pragma unroll
        for (int r = 0; r < 4; r++)
          Cp[(size_t)(rowb + r) * N + col] = f2bf(acc[i][j][r] * s);
      }
    }
  } else {
    float* Cp = (float*)Cout;
#pragma unroll
    for (int i = 0; i < 4; i++) {
      int rowb = m0 + wm + i * 16 + quad * 4;
#pragma unroll
      for (int j = 0; j < 4; j++) {
        int col = n0 + wn + j * 16 + lane15;
        float bv = bias[col];
#pragma unroll
        for (int r = 0; r < 4; r++)
          Cp[(size_t)(rowb + r) * N + col] = acc[i][j][r] + bv;
      }
    }
  }
}

// V transpose: qkv V-block [tok][h*64+d] -> vT[(bh*64+d)][tok]
__global__ void k_vt(const unsigned short* __restrict__ qkv, unsigned short* __restrict__ vT) {
  __shared__ unsigned short T[64 * 65];
  int t = threadIdx.x;
  int bh = blockIdx.y, b = bh >> 4, h = bh & 15;
  int t0 = blockIdx.x * 64;
  int tokl = t >> 2, dl = (t & 3) * 16;
  const unsigned short* g = qkv + (size_t)(b * SEQ + t0 + tokl) * C3 + 2 * C1 + h * 64 + dl;
  short8 v0 = *(const short8*)g;
  short8 v1 = *(const short8*)(g + 8);
#pragma unroll
  for (int j = 0; j < 8; j++) {
    T[(dl + j) * 65 + tokl]     = (unsigned short)v0[j];
    T[(dl + 8 + j) * 65 + tokl] = (unsigned short)v1[j];
  }
  __syncthreads();
  int d2 = t >> 2, tk = (t & 3) * 16;
  union { unsigned short s[16]; short8 v[2]; } o;
#pragma unroll
  for (int j = 0; j < 16; j++) o.s[j] = T[d2 * 65 + tk + j];
  unsigned short* og = vT + ((size_t)bh * 64 + d2) * SEQ + t0 + tk;
  *(short8*)og = o.v[0];
  *(short8*)(og + 8) = o.v[1];
}

// Flash attention, 32x32x16 MFMA, 4 waves x 32 q = 128 q per block.
// Single 32 KB LDS buffer + 2-barrier staging; 128-key tile processed as two
// 64-key halves (stL[2] keeps live S-regs at 32 -> fits 3 blocks/CU at
// launch_bounds(256,3) WITHOUT scratch spill; round-3's st[w] dynamic index
// demoted the S-tile to scratch: 500 MB of spill writes).
__global__ __launch_bounds__(256, 3) void k_attn(
    const unsigned short* __restrict__ qkv, const unsigned short* __restrict__ vT,
    unsigned short* __restrict__ att)
{
  __shared__ unsigned short buf[16384];  // Ks 128x64 | Vt 64x128
  const int tid = threadIdx.x;
  const int w = tid >> 6, l = tid & 63;
  const int l31 = l & 31, hl = l >> 5;
  const int bh = blockIdx.x, b = bh >> 4, h = bh & 15;
  const int qt = (int)(gridDim.y - 1 - blockIdx.y);  // globally heavy-first
  const int q0 = qt * 128;
  const int nkt = qt + 1;
  const size_t tokb = (size_t)b * SEQ;
  const int qmy = q0 + w * 32 + l31;

  // Q B-frags (global, once): B[k=d][n=q], k = hl*8+j within kstep
  bf16x8 qf[4];
  {
    const unsigned short* qp = qkv + (tokb + q0 + w * 32 + l31) * C3 + h * 64 + hl * 8;
#pragma unroll
    for (int ks = 0; ks < 4; ks++) qf[ks] = *(const bf16x8*)(qp + ks * 16);
  }

  f32x16 O[2];
#pragma unroll
  for (int i = 0; i < 16; i++) { O[0][i] = 0.f; O[1][i] = 0.f; }
  float mrun = -1e30f, lrun = 0.f;

  const int krow_l = l >> 3, kslot = l & 7;
  const int vrow_l = l >> 4, vslot = l & 15;
  unsigned short* Kb = &buf[0];
  unsigned short* Vb = &buf[8192];

  for (int kt = 0; kt < nkt; kt++) {
    const int k0 = kt << 7;
    __syncthreads();  // prev-tile reads done
    {
#pragma unroll
      for (int i = 0; i < 4; i++) {
        int rb = (w * 4 + i) * 8;
        int row = rb + krow_l;
        int ck = kslot ^ (row & 7);
        const unsigned short* g = qkv + (tokb + k0 + row) * C3 + C1 + h * 64 + ck * 8;
        __builtin_amdgcn_global_load_lds((gv_t*)g, (lv_t*)&Kb[rb * 64], 16, 0, 0);
      }
#pragma unroll
      for (int i = 0; i < 4; i++) {
        int rb = (w * 4 + i) * 4;
        int row = rb + vrow_l;
        int ck = vslot ^ (row & 15);
        const unsigned short* g = vT + ((size_t)bh * 64 + row) * SEQ + k0 + ck * 8;
        __builtin_amdgcn_global_load_lds((gv_t*)g, (lv_t*)&Vb[rb * 128], 16, 0, 0);
      }
    }
    __syncthreads();  // staging landed

    const bool diag = (kt == nkt - 1);

#pragma unroll
    for (int ht = 0; ht < 2; ht++) {
      if (diag && (ht * 2 > w)) continue;     // whole half beyond diagonal
      const bool two = !diag || (ht * 2 + 1 <= w);

      // S^T = K @ Q^T for this 64-key half : C[key][q]
      f32x16 stL[2];
#pragma unroll
      for (int lm = 0; lm < 2; lm++) {
        if (lm == 1 && !two) continue;
#pragma unroll
        for (int i = 0; i < 16; i++) stL[lm][i] = 0.f;
        int row = (ht * 2 + lm) * 32 + l31;
        const unsigned short* kr = &Kb[row * 64];
#pragma unroll
        for (int ks = 0; ks < 4; ks++) {
          bf16x8 a = *(const bf16x8*)&kr[((((ks << 1) | hl)) ^ (row & 7)) * 8];
          stL[lm] = __builtin_amdgcn_mfma_f32_32x32x16_bf16(a, qf[ks], stL[lm], 0, 0, 0);
        }
      }

      if (diag) {  // partial mask in subtile mt == w (compile-time index, runtime compare)
#pragma unroll
        for (int lm = 0; lm < 2; lm++) {
          if (ht * 2 + lm == w) {
#pragma unroll
            for (int r = 0; r < 16; r++) {
              int key = k0 + w * 32 + (r & 3) + ((r >> 2) << 3) + (hl << 2);
              if (key > qmy) stL[lm][r] = -1e30f;
            }
          }
        }
      }

      float vmax = -1e30f;
#pragma unroll
      for (int lm = 0; lm < 2; lm++) {
        if (lm == 1 && !two) continue;
#pragma unroll
        for (int r = 0; r < 16; r++) vmax = fmaxf(vmax, stL[lm][r]);
      }
      vmax = fmaxf(vmax, __shfl_xor(vmax, 32, 64));
      float mnew = fmaxf(mrun, vmax);
      float alpha = EXP2(mrun - mnew);

      float psum = 0.f;
      unsigned pk[2][8];
#pragma unroll
      for (int lm = 0; lm < 2; lm++) {
        if (lm == 1 && !two) continue;
#pragma unroll
        for (int r = 0; r < 16; r++) {
          float pv = EXP2(stL[lm][r] - mnew);
          stL[lm][r] = pv;
          psum += pv;
        }
#pragma unroll
        for (int k2 = 0; k2 < 8; k2++)
          pk[lm][k2] = pk2(stL[lm][2 * k2], stL[lm][2 * k2 + 1]);
      }
      psum += __shfl_xor(psum, 32, 64);
      lrun = lrun * alpha + psum;
      mrun = mnew;

#pragma unroll
      for (int i = 0; i < 16; i++) { O[0][i] *= alpha; O[1][i] *= alpha; }

      // O^T += V^T @ P^T for this half (4 ksteps of 16 keys)
#pragma unroll
      for (int ks4 = 0; ks4 < 4; ks4++) {
        int lm = ks4 >> 1, e = ks4 & 1;
        if (lm == 1 && !two) continue;
        unsigned pA0 = pk[lm][4 * e], pA1 = pk[lm][4 * e + 1];
        unsigned pB0 = pk[lm][4 * e + 2], pB1 = pk[lm][4 * e + 3];
        unsigned w0 = hl ? pA0 : pB0, w1 = hl ? pA1 : pB1;
        unsigned r0 = (unsigned)__shfl_xor((int)w0, 32, 64);
        unsigned r1 = (unsigned)__shfl_xor((int)w1, 32, 64);
        unsigned s0 = hl ? pB0 : pA0, s1 = hl ? pB1 : pA1;
        union { unsigned u[4]; bf16x8 v; } Bf;
        Bf.u[0] = hl ? r0 : s0; Bf.u[1] = hl ? r1 : s1;
        Bf.u[2] = hl ? s0 : r0; Bf.u[3] = hl ? s1 : r1;
        int kk = ht * 4 + ks4;  // global kstep in tile
#pragma unroll
        for (int dt = 0; dt < 2; dt++) {
          int row = dt * 32 + l31;
          bf16x8 a = *(const bf16x8*)&Vb[row * 128 + (((2 * kk + hl)) ^ (row & 15)) * 8];
          O[dt] = __builtin_amdgcn_mfma_f32_32x32x16_bf16(a, Bf.v, O[dt], 0, 0, 0);
        }
      }
    }
  }

  // epilogue: O^T (C-layout) -> LDS [q][d] -> coalesced bf16 store
  __syncthreads();  // all waves done reading buf before overlay
  float linv = __builtin_amdgcn_rcpf(lrun);
  unsigned* epi32 = (unsigned*)&buf[0];
  const int base = w * 2304 + l31 * 72;
#pragma unroll
  for (int dt = 0; dt < 2; dt++)
#pragma unroll
    for (int c = 0; c < 4; c++) {
      int d0 = dt * 32 + c * 8 + hl * 4;
      epi32[(base + d0) >> 1]     = rne2(O[dt][4 * c] * linv, O[dt][4 * c + 1] * linv);
      epi32[(base + d0 + 2) >> 1] = rne2(O[dt][4 * c + 2] * linv, O[dt][4 * c + 3] * linv);
    }
  __builtin_amdgcn_s_waitcnt(0);  // lgkm drain before cross-lane read (same wave)
  {
    int q = l >> 1, hf = l & 1;
    const unsigned short* ep = &buf[w * 2304 + q * 72 + hf * 32];
    unsigned short* og = att + (tokb + q0 + w * 32 + q) * C1 + h * 64 + hf * 32;
#pragma unroll
    for (int c2 = 0; c2 < 4; c2++)
      *(bf16x8*)(og + c2 * 8) = *(const bf16x8*)&ep[c2 * 8];
  }
}

extern "C" void kernel_launch(void* const* d_in, const int* in_sizes, int n_in,
                              void* d_out, int out_size, void* d_ws, size_t ws_size,
                              hipStream_t stream) {
  const float* x     = (const float*)d_in[0];
  const float* w_qkv = (const float*)d_in[1];
  const float* w_out = (const float*)d_in[2];
  const float* b_out = (const float*)d_in[3];
  float* out = (float*)d_out;

  unsigned short* xb  = (unsigned short*)d_ws;
  unsigned short* wqb = xb  + (size_t)8192 * 1024;
  unsigned short* wob = wqb + (size_t)3072 * 1024;
  unsigned short* qkv = wob + (size_t)1024 * 1024;
  unsigned short* att = qkv + (size_t)8192 * 3072;
  unsigned short* vT  = att + (size_t)8192 * 1024;

  k_cvt<<<8192, 256, 0, stream>>>(x, xb, 8192 * 1024 / 4);
  k_cvt<<<3072, 256, 0, stream>>>(w_qkv, wqb, 3072 * 1024 / 4);
  k_cvt<<<1024, 256, 0, stream>>>(w_out, wob, 1024 * 1024 / 4);
  k_gemm<0><<<dim3(24, 64), 256, 0, stream>>>(xb, wqb, (void*)qkv, nullptr, 8192, 3072, 1024);
  k_vt<<<dim3(32, 64), 256, 0, stream>>>(qkv, vT);
  k_attn<<<dim3(64, 16), 256, 0, stream>>>(qkv, vT, att);
  k_gemm<1><<<dim3(8, 64), 256, 0, stream>>>(att, wob, (void*)out, b_out, 8192, 1024, 1024);
}